// Round 1
// baseline (50.209 us; speedup 1.0000x reference)
//
#include <hip/hip_runtime.h>
#include <math.h>

// Problem constants
#define NB 8
#define NN 128
#define NE 2
#define NDM 128
#define NH 4
static constexpr float NEGV = -1000000.0f;

// One workgroup per (b, r). 256 threads = 4 waves.
// lane l: e = l>>5, c4 = l&31 (float4 chunk of DM)
// wave w handles senders s = w + 4*si, si = 0..31, held in registers.
__global__ __launch_bounds__(256, 2)
void edge_attn_kernel(const float* __restrict__ edge_msgs,
                      const float* __restrict__ node_states,
                      const float* __restrict__ W,
                      const float* __restrict__ bvec,
                      const int*   __restrict__ edges,
                      float* __restrict__ out) {
    const int blk = blockIdx.x;
    const int b = blk >> 7;     // / 128
    const int r = blk & 127;

    const int t  = threadIdx.x;
    const int w  = t >> 6;      // wave 0..3
    const int l  = t & 63;      // lane 0..63
    const int e  = l >> 5;      // 0/1
    const int c4 = l & 31;      // float4 chunk over DM

    __shared__ float sval[128][2][4];    // raw scores [s][e][h]
    __shared__ float wts [128][2][4];    // softmax weights [s][e][h]
    __shared__ float ebias[128][2];      // mask bias
    __shared__ float nodep[4];           // node projection per h
    __shared__ float outbuf[4][4][128];  // [wave][h][c]

    // ---- W_msg fragment for this lane's c-chunk (same for both e halves)
    float4 wm[4];
    #pragma unroll
    for (int h = 0; h < 4; ++h)
        wm[h] = *(const float4*)(W + h * 256 + c4 * 4);

    // ---- node projection: wave 0 only, 64-lane reduce
    if (w == 0) {
        float2 nv = *(const float2*)(node_states + ((size_t)b * NN + r) * 128 + l * 2);
        float np0, np1, np2, np3;
        {
            float2 wn0 = *(const float2*)(W + 0 * 256 + 128 + l * 2);
            float2 wn1 = *(const float2*)(W + 1 * 256 + 128 + l * 2);
            float2 wn2 = *(const float2*)(W + 2 * 256 + 128 + l * 2);
            float2 wn3 = *(const float2*)(W + 3 * 256 + 128 + l * 2);
            np0 = nv.x * wn0.x + nv.y * wn0.y;
            np1 = nv.x * wn1.x + nv.y * wn1.y;
            np2 = nv.x * wn2.x + nv.y * wn2.y;
            np3 = nv.x * wn3.x + nv.y * wn3.y;
        }
        #pragma unroll
        for (int m = 32; m >= 1; m >>= 1) {
            np0 += __shfl_xor(np0, m);
            np1 += __shfl_xor(np1, m);
            np2 += __shfl_xor(np2, m);
            np3 += __shfl_xor(np3, m);
        }
        if (l == 0) { nodep[0] = np0; nodep[1] = np1; nodep[2] = np2; nodep[3] = np3; }
    }

    // ---- edge mask bias: 256 threads load one int each
    {
        int s  = t >> 1;
        int ec = t & 1;
        int ev = edges[(((size_t)b * NN + s) * NN + r) * 3 + 1 + ec];
        ebias[s][ec] = (1.0f - (float)ev) * NEGV;
    }

    // ---- Pass A: stream edge_msgs tile into registers (single HBM read)
    const float* base = edge_msgs
        + (size_t)b * NN * NN * NE * NDM
        + (size_t)r * NE * NDM
        + e * NDM + c4 * 4;
    // stride per sender s: NN*NE*NDM = 32768 floats

    float4 vreg[32];
    #pragma unroll
    for (int si = 0; si < 32; ++si)
        vreg[si] = *(const float4*)(base + (size_t)(w + 4 * si) * 32768);

    #pragma unroll
    for (int si = 0; si < 32; ++si) {
        float p0 = vreg[si].x * wm[0].x + vreg[si].y * wm[0].y + vreg[si].z * wm[0].z + vreg[si].w * wm[0].w;
        float p1 = vreg[si].x * wm[1].x + vreg[si].y * wm[1].y + vreg[si].z * wm[1].z + vreg[si].w * wm[1].w;
        float p2 = vreg[si].x * wm[2].x + vreg[si].y * wm[2].y + vreg[si].z * wm[2].z + vreg[si].w * wm[2].w;
        float p3 = vreg[si].x * wm[3].x + vreg[si].y * wm[3].y + vreg[si].z * wm[3].z + vreg[si].w * wm[3].w;
        // reduce over the 32 lanes of this e-half (masks <=16 stay in-half)
        #pragma unroll
        for (int m = 16; m >= 1; m >>= 1) {
            p0 += __shfl_xor(p0, m);
            p1 += __shfl_xor(p1, m);
            p2 += __shfl_xor(p2, m);
            p3 += __shfl_xor(p3, m);
        }
        if (c4 == 0) {
            int s = w + 4 * si;
            float4 pv; pv.x = p0; pv.y = p1; pv.z = p2; pv.w = p3;
            *(float4*)&sval[s][e][0] = pv;
        }
    }
    __syncthreads();

    // ---- Softmax over s per (e,h): 8 pairs x 32 lanes
    {
        int p  = t >> 5;        // 0..7
        int j  = t & 31;
        int es = p & 1;
        int h  = p >> 1;
        float bb = bvec[h] + nodep[h];
        float y0, y1, y2, y3;
        {
            float x;
            x = sval[j +  0][es][h] + bb; x = x > 0.f ? x : expm1f(x); y0 = x + ebias[j +  0][es];
            x = sval[j + 32][es][h] + bb; x = x > 0.f ? x : expm1f(x); y1 = x + ebias[j + 32][es];
            x = sval[j + 64][es][h] + bb; x = x > 0.f ? x : expm1f(x); y2 = x + ebias[j + 64][es];
            x = sval[j + 96][es][h] + bb; x = x > 0.f ? x : expm1f(x); y3 = x + ebias[j + 96][es];
        }
        float m4 = fmaxf(fmaxf(y0, y1), fmaxf(y2, y3));
        #pragma unroll
        for (int m = 16; m >= 1; m >>= 1) m4 = fmaxf(m4, __shfl_xor(m4, m));
        y0 = __expf(y0 - m4); y1 = __expf(y1 - m4);
        y2 = __expf(y2 - m4); y3 = __expf(y3 - m4);
        float sum = y0 + y1 + y2 + y3;
        #pragma unroll
        for (int m = 16; m >= 1; m >>= 1) sum += __shfl_xor(sum, m);
        float inv = 1.0f / sum;
        wts[j +  0][es][h] = y0 * inv;
        wts[j + 32][es][h] = y1 * inv;
        wts[j + 64][es][h] = y2 * inv;
        wts[j + 96][es][h] = y3 * inv;
    }
    __syncthreads();

    // ---- Pass B: weighted aggregation from register-resident tile
    float4 acc0 = {0,0,0,0}, acc1 = {0,0,0,0}, acc2 = {0,0,0,0}, acc3 = {0,0,0,0};
    #pragma unroll
    for (int si = 0; si < 32; ++si) {
        int s = w + 4 * si;
        float4 wt = *(const float4*)&wts[s][e][0];
        acc0.x += wt.x * vreg[si].x; acc0.y += wt.x * vreg[si].y; acc0.z += wt.x * vreg[si].z; acc0.w += wt.x * vreg[si].w;
        acc1.x += wt.y * vreg[si].x; acc1.y += wt.y * vreg[si].y; acc1.z += wt.y * vreg[si].z; acc1.w += wt.y * vreg[si].w;
        acc2.x += wt.z * vreg[si].x; acc2.y += wt.z * vreg[si].y; acc2.z += wt.z * vreg[si].z; acc2.w += wt.z * vreg[si].w;
        acc3.x += wt.w * vreg[si].x; acc3.y += wt.w * vreg[si].y; acc3.z += wt.w * vreg[si].z; acc3.w += wt.w * vreg[si].w;
    }
    // fold the two e halves: lane l and l^32 hold same c4
    acc0.x += __shfl_xor(acc0.x, 32); acc0.y += __shfl_xor(acc0.y, 32); acc0.z += __shfl_xor(acc0.z, 32); acc0.w += __shfl_xor(acc0.w, 32);
    acc1.x += __shfl_xor(acc1.x, 32); acc1.y += __shfl_xor(acc1.y, 32); acc1.z += __shfl_xor(acc1.z, 32); acc1.w += __shfl_xor(acc1.w, 32);
    acc2.x += __shfl_xor(acc2.x, 32); acc2.y += __shfl_xor(acc2.y, 32); acc2.z += __shfl_xor(acc2.z, 32); acc2.w += __shfl_xor(acc2.w, 32);
    acc3.x += __shfl_xor(acc3.x, 32); acc3.y += __shfl_xor(acc3.y, 32); acc3.z += __shfl_xor(acc3.z, 32); acc3.w += __shfl_xor(acc3.w, 32);

    if (e == 0) {
        *(float4*)&outbuf[w][0][c4 * 4] = acc0;
        *(float4*)&outbuf[w][1][c4 * 4] = acc1;
        *(float4*)&outbuf[w][2][c4 * 4] = acc2;
        *(float4*)&outbuf[w][3][c4 * 4] = acc3;
    }
    __syncthreads();

    // ---- cross-wave reduce + store (coalesced)
    #pragma unroll
    for (int k = 0; k < 2; ++k) {
        int idx = t + 256 * k;          // 0..511 = h*128 + c
        int h = idx >> 7;
        int c = idx & 127;
        float v = outbuf[0][h][c] + outbuf[1][h][c] + outbuf[2][h][c] + outbuf[3][h][c];
        out[((size_t)b * NN + r) * 512 + idx] = v;
    }
}

extern "C" void kernel_launch(void* const* d_in, const int* in_sizes, int n_in,
                              void* d_out, int out_size, void* d_ws, size_t ws_size,
                              hipStream_t stream) {
    const float* edge_msgs   = (const float*)d_in[0];
    const float* node_states = (const float*)d_in[1];
    const float* W           = (const float*)d_in[2];
    const float* bvec        = (const float*)d_in[3];
    const int*   edges       = (const int*)d_in[4];
    float* out = (float*)d_out;

    dim3 grid(NB * NN);
    dim3 block(256);
    edge_attn_kernel<<<grid, block, 0, stream>>>(edge_msgs, node_states, W, bvec, edges, out);
}

// Round 2
// 33.455 us; speedup vs baseline: 1.5008x; 1.5008x over previous
//
#include <hip/hip_runtime.h>
#include <math.h>

// Problem constants
#define NB 8
#define NN 128
static constexpr float NEGV = -1000000.0f;

// One workgroup per (b, r). 512 threads = 8 waves.
// lane l: e = l>>5, c4 = l&31 (float4 chunk of DM)
// wave w handles senders s = w + 8*si, si = 0..15, held in registers.
__global__ __launch_bounds__(512, 4)
void edge_attn_kernel(const float* __restrict__ edge_msgs,
                      const float* __restrict__ node_states,
                      const float* __restrict__ W,
                      const float* __restrict__ bvec,
                      const int*   __restrict__ edges,
                      float* __restrict__ out) {
    const int blk = blockIdx.x;
    const int b = blk >> 7;     // / 128
    const int r = blk & 127;

    const int t  = threadIdx.x;
    const int w  = t >> 6;      // wave 0..7
    const int l  = t & 63;      // lane 0..63
    const int e  = l >> 5;      // 0/1
    const int c4 = l & 31;      // float4 chunk over DM

    // part: per s (stride 68 floats, pad to de-conflict reads):
    //   [e*32 + h*8 + g] = quad-partial of score(s,e,h) for c4-quad-group g
    __shared__ float part[128 * 68];
    __shared__ float wts [128][2][4];    // softmax weights [s][e][h]
    __shared__ float ebias[128][2];      // mask bias
    __shared__ float nodep[4];           // node projection per h
    __shared__ float outbuf[8][4][128];  // [wave][h][c]

    // ---- W_msg fragment for this lane's c-chunk (same for both e halves)
    float4 wm0 = *(const float4*)(W +   0 + c4 * 4);
    float4 wm1 = *(const float4*)(W + 256 + c4 * 4);
    float4 wm2 = *(const float4*)(W + 512 + c4 * 4);
    float4 wm3 = *(const float4*)(W + 768 + c4 * 4);

    // ---- node projection: wave 0 only, 64-lane reduce
    if (w == 0) {
        float2 nv  = *(const float2*)(node_states + ((size_t)b * NN + r) * 128 + l * 2);
        float2 wn0 = *(const float2*)(W + 128 + l * 2);
        float2 wn1 = *(const float2*)(W + 384 + l * 2);
        float2 wn2 = *(const float2*)(W + 640 + l * 2);
        float2 wn3 = *(const float2*)(W + 896 + l * 2);
        float np0 = nv.x * wn0.x + nv.y * wn0.y;
        float np1 = nv.x * wn1.x + nv.y * wn1.y;
        float np2 = nv.x * wn2.x + nv.y * wn2.y;
        float np3 = nv.x * wn3.x + nv.y * wn3.y;
        #pragma unroll
        for (int m = 32; m >= 1; m >>= 1) {
            np0 += __shfl_xor(np0, m);
            np1 += __shfl_xor(np1, m);
            np2 += __shfl_xor(np2, m);
            np3 += __shfl_xor(np3, m);
        }
        if (l == 0) { nodep[0] = np0; nodep[1] = np1; nodep[2] = np2; nodep[3] = np3; }
    }

    // ---- edge mask bias: first 256 threads load one int each
    if (t < 256) {
        int s  = t >> 1;
        int ec = t & 1;
        int ev = edges[(((size_t)b * NN + s) * NN + r) * 3 + 1 + ec];
        ebias[s][ec] = (1.0f - (float)ev) * NEGV;
    }

    // ---- Stream edge_msgs tile into registers (single HBM read, coalesced 1KiB/wave-instr)
    const float* bp = edge_msgs
        + (size_t)b * (NN * NN * 256)
        + (size_t)r * 256
        + e * 128 + c4 * 4;
    // stride per sender s: NN*2*128 = 32768 floats

    float4 v[16];
    #pragma unroll
    for (int si = 0; si < 16; ++si)
        v[si] = *(const float4*)(bp + (size_t)(w + 8 * si) * 32768);

    // ---- Pass A: scores. Quad-reduce (masks 1,2 stay in-quad -> DPP),
    // swap-select so lane l&3 ends holding the h=(l&3) quad sum.
    const int hsel = l & 3;
    const int g    = (l >> 2) & 7;
    const bool o1  = (l & 1) != 0;
    const bool o2  = (l & 2) != 0;
    #pragma unroll
    for (int si = 0; si < 16; ++si) {
        int s = w + 8 * si;
        float p0 = v[si].x * wm0.x + v[si].y * wm0.y + v[si].z * wm0.z + v[si].w * wm0.w;
        float p1 = v[si].x * wm1.x + v[si].y * wm1.y + v[si].z * wm1.z + v[si].w * wm1.w;
        float p2 = v[si].x * wm2.x + v[si].y * wm2.y + v[si].z * wm2.z + v[si].w * wm2.w;
        float p3 = v[si].x * wm3.x + v[si].y * wm3.y + v[si].z * wm3.z + v[si].w * wm3.w;
        // mask-1: two values per shuffle via swap-select
        float x01 = o1 ? p1 : p0, y01 = o1 ? p0 : p1;
        float x23 = o1 ? p3 : p2, y23 = o1 ? p2 : p3;
        float r01 = x01 + __shfl_xor(y01, 1);   // even lanes: p0 pair-sum; odd: p1
        float r23 = x23 + __shfl_xor(y23, 1);   // even: p2; odd: p3
        // mask-2: one value per shuffle
        float x2 = o2 ? r23 : r01, y2 = o2 ? r01 : r23;
        float val = x2 + __shfl_xor(y2, 2);     // lane l&3 == h holds quad sum for h
        part[s * 68 + e * 32 + hsel * 8 + g] = val;
    }
    __syncthreads();

    // ---- Softmax over s per (e,h): 8 groups x 32 lanes (first 256 threads)
    if (t < 256) {
        int p  = t >> 5;        // 0..7
        int j  = t & 31;
        int es = p & 1;
        int h  = p >> 1;
        float bb = bvec[h] + nodep[h];
        float y0, y1, y2, y3;
        #define SCORE(k, dst)                                                  \
        {                                                                      \
            int s = j + 32 * k;                                                \
            const float* q = &part[s * 68 + es * 32 + h * 8];                  \
            float4 qa = *(const float4*)q;                                     \
            float4 qb = *(const float4*)(q + 4);                               \
            float x = (qa.x + qa.y + qa.z + qa.w)                              \
                    + (qb.x + qb.y + qb.z + qb.w) + bb;                        \
            x = x > 0.f ? x : expm1f(x);                                       \
            dst = x + ebias[s][es];                                            \
        }
        SCORE(0, y0) SCORE(1, y1) SCORE(2, y2) SCORE(3, y3)
        #undef SCORE
        float m4 = fmaxf(fmaxf(y0, y1), fmaxf(y2, y3));
        #pragma unroll
        for (int m = 16; m >= 1; m >>= 1) m4 = fmaxf(m4, __shfl_xor(m4, m));
        y0 = __expf(y0 - m4); y1 = __expf(y1 - m4);
        y2 = __expf(y2 - m4); y3 = __expf(y3 - m4);
        float sum = y0 + y1 + y2 + y3;
        #pragma unroll
        for (int m = 16; m >= 1; m >>= 1) sum += __shfl_xor(sum, m);
        float inv = 1.0f / sum;
        wts[j +  0][es][h] = y0 * inv;
        wts[j + 32][es][h] = y1 * inv;
        wts[j + 64][es][h] = y2 * inv;
        wts[j + 96][es][h] = y3 * inv;
    }
    __syncthreads();

    // ---- Pass B: weighted aggregation from register-resident tile
    float4 a0 = {0,0,0,0}, a1 = {0,0,0,0}, a2 = {0,0,0,0}, a3 = {0,0,0,0};
    #pragma unroll
    for (int si = 0; si < 16; ++si) {
        int s = w + 8 * si;
        float4 wt = *(const float4*)&wts[s][e][0];
        a0.x += wt.x * v[si].x; a0.y += wt.x * v[si].y; a0.z += wt.x * v[si].z; a0.w += wt.x * v[si].w;
        a1.x += wt.y * v[si].x; a1.y += wt.y * v[si].y; a1.z += wt.y * v[si].z; a1.w += wt.y * v[si].w;
        a2.x += wt.z * v[si].x; a2.y += wt.z * v[si].y; a2.z += wt.z * v[si].z; a2.w += wt.z * v[si].w;
        a3.x += wt.w * v[si].x; a3.y += wt.w * v[si].y; a3.z += wt.w * v[si].z; a3.w += wt.w * v[si].w;
    }
    // fold the two e halves: lane l and l^32 hold the same c4
    a0.x += __shfl_xor(a0.x, 32); a0.y += __shfl_xor(a0.y, 32); a0.z += __shfl_xor(a0.z, 32); a0.w += __shfl_xor(a0.w, 32);
    a1.x += __shfl_xor(a1.x, 32); a1.y += __shfl_xor(a1.y, 32); a1.z += __shfl_xor(a1.z, 32); a1.w += __shfl_xor(a1.w, 32);
    a2.x += __shfl_xor(a2.x, 32); a2.y += __shfl_xor(a2.y, 32); a2.z += __shfl_xor(a2.z, 32); a2.w += __shfl_xor(a2.w, 32);
    a3.x += __shfl_xor(a3.x, 32); a3.y += __shfl_xor(a3.y, 32); a3.z += __shfl_xor(a3.z, 32); a3.w += __shfl_xor(a3.w, 32);

    if (e == 0) {
        *(float4*)&outbuf[w][0][c4 * 4] = a0;
        *(float4*)&outbuf[w][1][c4 * 4] = a1;
        *(float4*)&outbuf[w][2][c4 * 4] = a2;
        *(float4*)&outbuf[w][3][c4 * 4] = a3;
    }
    __syncthreads();

    // ---- cross-wave reduce + coalesced store: t = h*128 + c
    {
        int h = t >> 7;
        int c = t & 127;
        float sv = 0.f;
        #pragma unroll
        for (int k = 0; k < 8; ++k) sv += outbuf[k][h][c];
        out[((size_t)b * NN + r) * 512 + t] = sv;
    }
}

extern "C" void kernel_launch(void* const* d_in, const int* in_sizes, int n_in,
                              void* d_out, int out_size, void* d_ws, size_t ws_size,
                              hipStream_t stream) {
    const float* edge_msgs   = (const float*)d_in[0];
    const float* node_states = (const float*)d_in[1];
    const float* W           = (const float*)d_in[2];
    const float* bvec        = (const float*)d_in[3];
    const int*   edges       = (const int*)d_in[4];
    float* out = (float*)d_out;

    dim3 grid(NB * NN);
    dim3 block(512);
    edge_attn_kernel<<<grid, block, 0, stream>>>(edge_msgs, node_states, W, bvec, edges, out);
}